// Round 11
// baseline (3498.902 us; speedup 1.0000x reference)
//
#include <hip/hip_runtime.h>
#include <stdint.h>

typedef unsigned long long u64;
typedef unsigned int u32;

// anchor (w,h) per a = ratio_idx*3 + scale_idx ; ratios (.5,1,2), scales (8,16,32)
__constant__ float c_aw[9] = {184.f,368.f,736.f,128.f,256.f,512.f, 88.f,176.f,352.f};
__constant__ float c_ah[9] = { 96.f,192.f,384.f,128.f,256.f,512.f,176.f,352.f,704.f};

// -------- w1 reorder: w1[co][ci*9+k] -> wt2[g][ci][k][m], co = g*8+m ----------
__global__ __launch_bounds__(256) void transpose_k(const float* __restrict__ w1,
                                                   float* __restrict__ wt2) {
  int e = blockIdx.x * 256 + threadIdx.x;   // < 2359296 exactly
  int m = e & 7;
  int t = e >> 3;
  int k = t % 9;
  int r = t / 9;          // g*512 + ci
  int ci = r & 511;
  int g = r >> 9;
  wt2[e] = w1[(size_t)(g * 8 + m) * 4608 + ci * 9 + k];
}

// ---------------- conv1: x(4,512,96,160) * w s2 p1 -> feat(4,512,48,80)
// ROUND-8 VERSION (96% of fp32-vector roofline: 922 us floor, 961 us measured).
__global__ __launch_bounds__(256, 3) void conv1_k(const float* __restrict__ x,
                                                  const float* __restrict__ wt2,
                                                  const float* __restrict__ b1,
                                                  float* __restrict__ feat) {
  __shared__ float xs[8 * 9 * 164];   // [ci][ih(9)][iw(161) pad 164] = 47232 B
  const int tid = threadIdx.x;
  const int lane = tid & 63;
  const int wv = __builtin_amdgcn_readfirstlane(tid >> 6);   // wave id 0..3
  const int owg = lane & 15;          // 16 groups of 5 ow
  const int ohl = lane >> 4;          // 0..3
  const int n = blockIdx.z;
  const int gg = blockIdx.x * 4 + wv; // global co-group, co = gg*8+m
  const int oh0 = blockIdx.y * 4;
  const int ih_base = 2 * oh0 - 1;

  // ---- c0-invariant staging descriptors (6 strided passes over 1449 elems) ----
  int soff[6], loff[6];
  float okf[6];
  bool act[6];
#pragma unroll
  for (int it = 0; it < 6; ++it) {
    int e2 = tid + 256 * it;
    act[it] = (e2 < 1449);
    int e = act[it] ? e2 : 0;
    int ih = e / 161;
    int c = e - ih * 161;
    int gih = ih_base + ih;
    int giw = c - 1;
    bool ok = act[it] && ((unsigned)gih < 96u) && ((unsigned)giw < 160u);
    soff[it] = min(max(gih, 0), 95) * 160 + min(max(giw, 0), 159);
    loff[it] = ih * 164 + c;
    okf[it] = ok ? 1.f : 0.f;
  }

  float acc[8][5];
#pragma unroll
  for (int m = 0; m < 8; ++m)
#pragma unroll
    for (int j = 0; j < 5; ++j) acc[m][j] = 0.f;

  const float* xb = x + (size_t)n * 512 * 96 * 160;
  const float* wgb = wt2 + (size_t)gg * 512 * 72;   // [ci][k(9)][m(8)]

  // prologue: load chunk c0=0 into regs
  float r[6][8];
#pragma unroll
  for (int it = 0; it < 6; ++it)
#pragma unroll
    for (int ci = 0; ci < 8; ++ci)
      r[it][ci] = xb[(size_t)ci * 15360 + soff[it]];

  for (int c0 = 0; c0 < 512; c0 += 8) {
    __syncthreads();   // previous compute finished; xs free for overwrite
#pragma unroll
    for (int it = 0; it < 6; ++it) {
      if (act[it]) {
        const float m_ = okf[it];
#pragma unroll
        for (int ci = 0; ci < 8; ++ci)
          xs[loff[it] + ci * 1476] = m_ * r[it][ci];   // 1476 = 9*164
      }
    }
    __syncthreads();
    // issue prefetch for c0+8 (fly during compute below)
    if (c0 + 8 < 512) {
      const float* xn = xb + (size_t)(c0 + 8) * 15360;
#pragma unroll
      for (int it = 0; it < 6; ++it)
#pragma unroll
        for (int ci = 0; ci < 8; ++ci)
          r[it][ci] = xn[(size_t)ci * 15360 + soff[it]];
    }

    for (int ci = 0; ci < 8; ++ci) {
      const float* wp = wgb + (size_t)(c0 + ci) * 72;   // wave-uniform
      const float* xrow = &xs[(ci * 9 + 2 * ohl) * 164 + owg * 10];
#pragma unroll
      for (int kh = 0; kh < 3; ++kh) {
        float xv[12];
        const float* xr = xrow + kh * 164;
#pragma unroll
        for (int t2 = 0; t2 < 6; ++t2) {          // 8B-aligned b64 LDS reads
          float2 tt = *(const float2*)(xr + 2 * t2);
          xv[2 * t2] = tt.x; xv[2 * t2 + 1] = tt.y;
        }
#pragma unroll
        for (int kw = 0; kw < 3; ++kw) {
          const float* wk = wp + (kh * 3 + kw) * 8;
#pragma unroll
          for (int j = 0; j < 5; ++j) {
            const float xj = xv[kw + 2 * j];
            acc[0][j] += wk[0] * xj; acc[1][j] += wk[1] * xj;
            acc[2][j] += wk[2] * xj; acc[3][j] += wk[3] * xj;
            acc[4][j] += wk[4] * xj; acc[5][j] += wk[5] * xj;
            acc[6][j] += wk[6] * xj; acc[7][j] += wk[7] * xj;
          }
        }
      }
    }
  }
  // epilogue
  const int oh = oh0 + ohl;
  const int owb = owg * 5;
#pragma unroll
  for (int m = 0; m < 8; ++m) {
    const int co = gg * 8 + m;
    const float bv = b1[co];
    float* op = &feat[(((size_t)n * 512 + co) * 48 + oh) * 80 + owb];
#pragma unroll
    for (int j = 0; j < 5; ++j) op[j] = acc[m][j] + bv;
  }
}

// ---------------- fused heads: blocks [0,120) = conv2 (1x1 bbox), [120,312) = conv3 (3x3 cls)
__global__ __launch_bounds__(256) void heads_k(const float* __restrict__ feat,
                                               const float* __restrict__ wb,
                                               const float* __restrict__ bb,
                                               const float* __restrict__ wcg,
                                               const float* __restrict__ bc,
                                               float* __restrict__ deltas,
                                               float* __restrict__ s) {
  __shared__ float smem[5328];
  const int tid = threadIdx.x;

  if (blockIdx.x < 120) {
    // ---- conv2: 1x1, feat -> deltas[b][pos][36] ----
    float* fs  = smem;          // 16*128
    float* wsb = smem + 2048;   // 16*36
    const int blk = blockIdx.x;
    const int b = blk / 30;
    const int pos0 = (blk % 30) * 128;
    const int pl = tid >> 1, cg = tid & 1;
    const int cbase = cg * 18;
    float acc[18];
#pragma unroll
    for (int j = 0; j < 18; ++j) acc[j] = 0.f;
    const float* fb = feat + (size_t)b * 512 * 3840;

    for (int c0 = 0; c0 < 512; c0 += 16) {
      for (int e = tid; e < 16 * 128; e += 256)
        fs[e] = fb[(size_t)(c0 + (e >> 7)) * 3840 + pos0 + (e & 127)];
      for (int e = tid; e < 16 * 36; e += 256) {
        int ci = e / 36, c = e - ci * 36;
        wsb[e] = wb[(size_t)c * 512 + c0 + ci];
      }
      __syncthreads();
      for (int ci = 0; ci < 16; ++ci) {
        float xv = fs[ci * 128 + pl];
#pragma unroll
        for (int j = 0; j < 18; ++j) acc[j] += xv * wsb[ci * 36 + cbase + j];
      }
      __syncthreads();
    }
    size_t o = ((size_t)b * 3840 + pos0 + pl) * 36 + cbase;
#pragma unroll
    for (int j = 0; j < 18; ++j) deltas[o + j] = acc[j] + bb[cbase + j];
  } else {
    // ---- conv3: 3x3 p1, cls channels 9..17 -> s[b][pos*9+a] ----
    float (*fs)[3][84] = (float(*)[3][84])smem;           // 16*3*84 = 4032
    float (*wc)[9][9]  = (float(*)[9][9])(smem + 4032);   // 16*81 = 1296
    const int bid2 = blockIdx.x - 120;
    const int oh = bid2 % 48;
    const int b = bid2 / 48;
    const int pos = tid % 80;
    const int cg = tid / 80;          // 0..3 (cg==3 idle for compute)
    float acc[3] = {0.f, 0.f, 0.f};
    const float* fb = feat + (size_t)b * 512 * 3840;

    for (int c0 = 0; c0 < 512; c0 += 16) {
      for (int e = tid; e < 16 * 246; e += 256) {
        int ci = e / 246;
        int r = e - ci * 246;
        int ihl = r / 82;
        int iw = r - ihl * 82 - 1;
        int gih = oh - 1 + ihl;
        float v = 0.f;
        if ((unsigned)gih < 48u && (unsigned)iw < 80u)
          v = fb[(size_t)(c0 + ci) * 3840 + gih * 80 + iw];
        fs[ci][ihl][iw + 1] = v;
      }
      for (int e = tid; e < 16 * 81; e += 256) {
        int ci = e / 81;
        int r = e - ci * 81;
        int co = r / 9;
        int k = r - co * 9;
        wc[ci][co][k] = wcg[((size_t)(9 + co) * 512 + c0 + ci) * 9 + k];
      }
      __syncthreads();
      if (cg < 3) {
        const int cb = cg * 3;
        for (int ci = 0; ci < 16; ++ci) {
#pragma unroll
          for (int kh = 0; kh < 3; ++kh) {
#pragma unroll
            for (int kw = 0; kw < 3; ++kw) {
              float xv = fs[ci][kh][pos + kw];
              acc[0] += xv * wc[ci][cb + 0][kh * 3 + kw];
              acc[1] += xv * wc[ci][cb + 1][kh * 3 + kw];
              acc[2] += xv * wc[ci][cb + 2][kh * 3 + kw];
            }
          }
        }
      }
      __syncthreads();
    }
    if (cg < 3) {
      const int cb = cg * 3;
      size_t o = (size_t)b * 34560 + ((size_t)oh * 80 + pos) * 9 + cb;
#pragma unroll
      for (int j = 0; j < 3; ++j) s[o + j] = acc[j] + bc[9 + cb + j];
    }
  }
}

// ---------------- decode: anchors + deltas -> boxes, filtered score keys ----------------
__global__ __launch_bounds__(256) void decode_k(const float* __restrict__ deltas,
                                                const float* __restrict__ s,
                                                float* __restrict__ boxes,
                                                u64* __restrict__ keys) {
  const int g = blockIdx.x * 256 + threadIdx.x;  // < 138240 exactly
  const int b = g / 34560;
  const int i = g - b * 34560;
  const int pos = i / 9;
  const int a = i - pos * 9;
  const int h = pos / 80;
  const int w = pos - h * 80;
  const float gx = (float)(w * 32);
  const float gy = (float)(h * 32);
  const float aw = c_aw[a], ah = c_ah[a];
  const float x1a = 7.5f - 0.5f * (aw - 1.f);   // exact
  const float y1a = 7.5f - 0.5f * (ah - 1.f);   // exact
  const float ws_ = aw, hs_ = ah;               // x2-x1+1 exact
  const float cx = (gx + x1a) + 0.5f * ws_;     // exact
  const float cy = (gy + y1a) + 0.5f * hs_;     // exact

  const float* dp = &deltas[((size_t)b * 3840 + pos) * 36 + a * 4];
  const float d0 = dp[0], d1 = dp[1], d2 = dp[2], d3 = dp[3];
  const float pcx = __fadd_rn(__fmul_rn(d0, ws_), cx);
  const float pcy = __fadd_rn(__fmul_rn(d1, hs_), cy);
  const float pw = __fmul_rn(expf(d2), ws_);
  const float ph = __fmul_rn(expf(d3), hs_);
  float bx1 = __fsub_rn(pcx, __fmul_rn(0.5f, pw));
  float by1 = __fsub_rn(pcy, __fmul_rn(0.5f, ph));
  float bx2 = __fadd_rn(pcx, __fmul_rn(0.5f, pw));
  float by2 = __fadd_rn(pcy, __fmul_rn(0.5f, ph));
  bx1 = fminf(fmaxf(bx1, 0.f), 2559.f);
  by1 = fminf(fmaxf(by1, 0.f), 1535.f);
  bx2 = fminf(fmaxf(bx2, 0.f), 2559.f);
  by2 = fminf(fmaxf(by2, 0.f), 1535.f);
  const float bw = __fadd_rn(__fsub_rn(bx2, bx1), 1.f);
  const float bh = __fadd_rn(__fsub_rn(by2, by1), 1.f);
  float sc = s[g];
  if (!(bw >= 16.f && bh >= 16.f)) sc = -1e30f;

  float4 bo;
  bo.x = bx1; bo.y = by1; bo.z = bx2; bo.w = by2;
  *(float4*)&boxes[(size_t)g * 4] = bo;

  u32 sb = __float_as_uint(sc);
  u32 ou = (sb & 0x80000000u) ? ~sb : (sb | 0x80000000u);
  keys[g] = ((u64)ou << 32) | (u32)(~(u32)i);
}

// ---- select+compact, 2-phase: 14-bit histogram (boundary bin) + exact-rank placement.
__global__ __launch_bounds__(1024) void selcomp_k(const u64* __restrict__ keys,
                                                  u64* __restrict__ sel) {
  __shared__ u32 h[16384];        // 64 KB
  __shared__ u64 cand[6144];      // 48 KB
  __shared__ u32 wsum[16], wsuf[16];
  __shared__ int s_bin, s_above, s_main, s_nc;
  const int b = blockIdx.x;
  const int tid = threadIdx.x;
  const int lane = tid & 63;
  const int wv = tid >> 6;
  const u64* kb = keys + (size_t)b * 34560;

  // phase A: histogram of top-14 bits
#pragma unroll
  for (int q = 0; q < 16; ++q) h[tid + 1024 * q] = 0;
  __syncthreads();
  for (int i = tid; i < 34560; i += 1024)
    atomicAdd(&h[(u32)(kb[i] >> 50)], 1u);
  __syncthreads();

  // hierarchical suffix-sum (3 barriers): thread owns bins [tid*16, tid*16+16)
  const int i0 = tid * 16;
  u32 myb[16];
  u32 tsum = 0;
#pragma unroll
  for (int q = 0; q < 16; ++q) { myb[q] = h[i0 + q]; tsum += myb[q]; }
  u32 sfx = tsum;
#pragma unroll
  for (int off = 1; off < 64; off <<= 1) {
    u32 o = __shfl_down(sfx, off, 64);
    if (lane + off < 64) sfx += o;
  }
  if (lane == 0) wsum[wv] = sfx;   // wave total
  __syncthreads();
  if (tid < 16) {
    u32 v = wsum[tid];
#pragma unroll
    for (int off = 1; off < 16; off <<= 1) {
      u32 o = __shfl_down(v, off, 64);
      if (tid + off < 16) v += o;
    }
    wsuf[tid] = v;                 // sum of wsum[w >= tid]
  }
  __syncthreads();
  const u32 wave_base = (wv < 15) ? wsuf[wv + 1] : 0u;
  u32 accu = wave_base + (sfx - tsum);
#pragma unroll
  for (int q = 15; q >= 0; --q) { accu += myb[q]; h[i0 + q] = accu; }  // suffix incl.
  __syncthreads();

  // boundary bin: h[bin] >= 2000 > h[bin+1]
#pragma unroll
  for (int q = 0; q < 16; ++q) {
    int bn = i0 + q;
    u32 Si = h[bn];
    u32 Sn = (bn < 16383) ? h[bn + 1] : 0u;
    if ((int)Si >= 2000 && (int)Sn < 2000) { s_bin = bn; s_above = (int)Sn; }
  }
  if (tid == 0) { s_main = 0; s_nc = 0; }
  __syncthreads();
  const u32 B = (u32)s_bin;
  const int above = s_above;
  const int need = 2000 - above;

  // phase B: compact mains, gather boundary-bin candidates
  for (int i = tid; i < 34560; i += 1024) {
    u64 k = kb[i];
    u32 t14 = (u32)(k >> 50);
    if (t14 > B) {
      int p = atomicAdd(&s_main, 1);
      sel[(size_t)b * 2048 + p] = k;
    } else if (t14 == B) {
      int p = atomicAdd(&s_nc, 1);
      if (p < 6144) cand[p] = k;
    }
  }
  __syncthreads();
  const int nc = min(s_nc, 6144);
  // exact rank among candidates (unique u64 keys): place top `need`
  for (int c = tid; c < nc; c += 1024) {
    u64 kc = cand[c];
    int rnk = 0;
    for (int j = 0; j < nc; ++j) rnk += (cand[j] > kc) ? 1 : 0;
    if (rnk < need) sel[(size_t)b * 2048 + above + rnk] = kc;
  }
}

// ---------------- fused sort(2048, 1024 thr) + single-wave greedy NMS (no barriers) ----
__global__ __launch_bounds__(1024) void nms2_k(const u64* __restrict__ sel,
                                               const float* __restrict__ boxes,
                                               float* __restrict__ out) {
  __shared__ u64 K[2048];
  __shared__ float bx1[2048], by1[2048], bx2[2048], by2[2048], ar[2048];
  __shared__ unsigned char val[2048];
  const int b = blockIdx.x;
  const int tid = threadIdx.x;

  for (int i = tid; i < 2048; i += 1024)
    K[i] = (i < 2000) ? sel[(size_t)b * 2048 + i] : 0ull;
  __syncthreads();
  // bitonic sort descending (1024 threads, 66 stages)
  for (int k2 = 2; k2 <= 2048; k2 <<= 1) {
    for (int j = k2 >> 1; j > 0; j >>= 1) {
      for (int i = tid; i < 2048; i += 1024) {
        int l = i ^ j;
        if (l > i) {
          u64 a = K[i], c = K[l];
          bool up = ((i & k2) == 0);
          if (up ? (a < c) : (a > c)) { K[i] = c; K[l] = a; }
        }
      }
      __syncthreads();
    }
  }
  // extract boxes/validity in score order
  for (int i = tid; i < 2048; i += 1024) {
    if (i < 2000) {
      u64 key = K[i];
      u32 ou = (u32)(key >> 32);
      int idx = (int)(~(u32)key);
      u32 sb = (ou & 0x80000000u) ? (ou & 0x7FFFFFFFu) : ~ou;
      float sc = __uint_as_float(sb);
      const float4 bo = *(const float4*)&boxes[((size_t)b * 34560 + idx) * 4];
      bx1[i] = bo.x; by1[i] = bo.y; bx2[i] = bo.z; by2[i] = bo.w;
      ar[i] = __fmul_rn(__fadd_rn(__fsub_rn(bo.z, bo.x), 1.f),
                        __fadd_rn(__fsub_rn(bo.w, bo.y), 1.f));
      val[i] = (sc > -5e29f) ? 1 : 0;
    } else {
      bx1[i] = 0.f; by1[i] = 0.f; bx2[i] = 0.f; by2[i] = 0.f; ar[i] = 1.f;
      val[i] = 0;
    }
  }
  __syncthreads();

  // ---- single-wave greedy NMS: lane owns boxes [32*lane, 32*lane+32) as u32 bitset
  if (tid < 64) {
    const int lane = tid;
    u32 v = 0;
#pragma unroll
    for (int q = 0; q < 32; ++q)
      v |= (val[lane * 32 + q] ? 1u : 0u) << q;

    int cnt = 0;
    for (int t = 0; t < 300; ++t) {
      u64 m = __ballot(v != 0);
      if (m == 0) break;
      const int f = __ffsll(m) - 1;
      const u32 fw = __shfl(v, f, 64);
      const int p = f * 32 + (__ffs(fw) - 1);    // first valid = pick
      const float px1 = bx1[p], py1 = by1[p], px2 = bx2[p], py2 = by2[p], pa = ar[p];
      if (lane == 0) {
        float* row = out + ((size_t)b * 300 + t) * 5;
        row[0] = (float)b; row[1] = px1; row[2] = py1; row[3] = px2; row[4] = py2;
      }
      cnt = t + 1;
      // suppress among my set bits (diagonal IoU=1 clears the pick itself)
      u32 rem = v;
      while (rem) {
        const int q = __ffs(rem) - 1;
        rem &= rem - 1;
        const int j = lane * 32 + q;
        float iw = __fadd_rn(__fsub_rn(fminf(px2, bx2[j]), fmaxf(px1, bx1[j])), 1.f);
        iw = fmaxf(0.f, iw);
        float ih = __fadd_rn(__fsub_rn(fminf(py2, by2[j]), fmaxf(py1, by1[j])), 1.f);
        ih = fmaxf(0.f, ih);
        const float inter = __fmul_rn(iw, ih);
        const float denom = __fsub_rn(__fadd_rn(pa, ar[j]), inter);
        const float iou = __fdiv_rn(inter, denom);
        if (iou > 0.7f) v &= ~(1u << q);
      }
    }
    // zero-fill remaining rows + count
    for (int t2 = cnt + lane; t2 < 300; t2 += 64) {
      float* row = out + ((size_t)b * 300 + t2) * 5;
      row[0] = (float)b; row[1] = 0.f; row[2] = 0.f; row[3] = 0.f; row[4] = 0.f;
    }
    if (lane == 0) out[6000 + b] = (float)cnt;
  }
}

// ---------------- launcher ----------------
extern "C" void kernel_launch(void* const* d_in, const int* in_sizes, int n_in,
                              void* d_out, int out_size, void* d_ws, size_t ws_size,
                              hipStream_t stream) {
  const float* x  = (const float*)d_in[0];
  const float* w1 = (const float*)d_in[1];
  const float* b1 = (const float*)d_in[2];
  const float* wb = (const float*)d_in[3];
  const float* bb = (const float*)d_in[4];
  const float* wc = (const float*)d_in[5];
  const float* bc = (const float*)d_in[6];
  float* out = (float*)d_out;
  char* ws = (char*)d_ws;

  float* feat   = (float*)(ws + 0);           // 31,457,280 B
  float* wt2    = (float*)(ws + 31457280);    //  9,437,184 B
  float* deltas = (float*)(ws + 40894464);    //  2,211,840 B
  float* s      = (float*)(ws + 43106304);    //    552,960 B
  float* boxes  = (float*)(ws + 43659264);    //  2,211,840 B
  u64*   keys   = (u64*)  (ws + 45871104);    //  1,105,920 B
  u64*   sel    = (u64*)  (ws + 46977088);    //     65,536 B

  hipLaunchKernelGGL(transpose_k, dim3(9216), dim3(256), 0, stream, w1, wt2);
  hipLaunchKernelGGL(conv1_k, dim3(16, 12, 4), dim3(256), 0, stream, x, wt2, b1, feat);
  hipLaunchKernelGGL(heads_k, dim3(312), dim3(256), 0, stream, feat, wb, bb, wc, bc, deltas, s);
  hipLaunchKernelGGL(decode_k, dim3(540), dim3(256), 0, stream, deltas, s, boxes, keys);
  hipLaunchKernelGGL(selcomp_k, dim3(4), dim3(1024), 0, stream, keys, sel);
  hipLaunchKernelGGL(nms2_k, dim3(4), dim3(1024), 0, stream, sel, boxes, out);
}

// Round 12
// 1543.610 us; speedup vs baseline: 2.2667x; 2.2667x over previous
//
#include <hip/hip_runtime.h>
#include <stdint.h>

typedef unsigned long long u64;
typedef unsigned int u32;

// anchor (w,h) per a = ratio_idx*3 + scale_idx ; ratios (.5,1,2), scales (8,16,32)
__constant__ float c_aw[9] = {184.f,368.f,736.f,128.f,256.f,512.f, 88.f,176.f,352.f};
__constant__ float c_ah[9] = { 96.f,192.f,384.f,128.f,256.f,512.f,176.f,352.f,704.f};

// -------- w1 reorder: w1[co][ci*9+k] -> wt2[g][ci][k][m], co = g*8+m ----------
__global__ __launch_bounds__(256) void transpose_k(const float* __restrict__ w1,
                                                   float* __restrict__ wt2) {
  int e = blockIdx.x * 256 + threadIdx.x;   // < 2359296 exactly
  int m = e & 7;
  int t = e >> 3;
  int k = t % 9;
  int r = t / 9;          // g*512 + ci
  int ci = r & 511;
  int g = r >> 9;
  wt2[e] = w1[(size_t)(g * 8 + m) * 4608 + ci * 9 + k];
}

// ---------------- conv1: x(4,512,96,160) * w s2 p1 -> feat(4,512,48,80)
// ROUND-8 VERSION (96% of fp32-vector roofline: 922 us floor, 961 us measured).
__global__ __launch_bounds__(256, 3) void conv1_k(const float* __restrict__ x,
                                                  const float* __restrict__ wt2,
                                                  const float* __restrict__ b1,
                                                  float* __restrict__ feat) {
  __shared__ float xs[8 * 9 * 164];   // [ci][ih(9)][iw(161) pad 164] = 47232 B
  const int tid = threadIdx.x;
  const int lane = tid & 63;
  const int wv = __builtin_amdgcn_readfirstlane(tid >> 6);   // wave id 0..3
  const int owg = lane & 15;          // 16 groups of 5 ow
  const int ohl = lane >> 4;          // 0..3
  const int n = blockIdx.z;
  const int gg = blockIdx.x * 4 + wv; // global co-group, co = gg*8+m
  const int oh0 = blockIdx.y * 4;
  const int ih_base = 2 * oh0 - 1;

  // ---- c0-invariant staging descriptors (6 strided passes over 1449 elems) ----
  int soff[6], loff[6];
  float okf[6];
  bool act[6];
#pragma unroll
  for (int it = 0; it < 6; ++it) {
    int e2 = tid + 256 * it;
    act[it] = (e2 < 1449);
    int e = act[it] ? e2 : 0;
    int ih = e / 161;
    int c = e - ih * 161;
    int gih = ih_base + ih;
    int giw = c - 1;
    bool ok = act[it] && ((unsigned)gih < 96u) && ((unsigned)giw < 160u);
    soff[it] = min(max(gih, 0), 95) * 160 + min(max(giw, 0), 159);
    loff[it] = ih * 164 + c;
    okf[it] = ok ? 1.f : 0.f;
  }

  float acc[8][5];
#pragma unroll
  for (int m = 0; m < 8; ++m)
#pragma unroll
    for (int j = 0; j < 5; ++j) acc[m][j] = 0.f;

  const float* xb = x + (size_t)n * 512 * 96 * 160;
  const float* wgb = wt2 + (size_t)gg * 512 * 72;   // [ci][k(9)][m(8)]

  // prologue: load chunk c0=0 into regs
  float r[6][8];
#pragma unroll
  for (int it = 0; it < 6; ++it)
#pragma unroll
    for (int ci = 0; ci < 8; ++ci)
      r[it][ci] = xb[(size_t)ci * 15360 + soff[it]];

  for (int c0 = 0; c0 < 512; c0 += 8) {
    __syncthreads();   // previous compute finished; xs free for overwrite
#pragma unroll
    for (int it = 0; it < 6; ++it) {
      if (act[it]) {
        const float m_ = okf[it];
#pragma unroll
        for (int ci = 0; ci < 8; ++ci)
          xs[loff[it] + ci * 1476] = m_ * r[it][ci];   // 1476 = 9*164
      }
    }
    __syncthreads();
    // issue prefetch for c0+8 (fly during compute below)
    if (c0 + 8 < 512) {
      const float* xn = xb + (size_t)(c0 + 8) * 15360;
#pragma unroll
      for (int it = 0; it < 6; ++it)
#pragma unroll
        for (int ci = 0; ci < 8; ++ci)
          r[it][ci] = xn[(size_t)ci * 15360 + soff[it]];
    }

    for (int ci = 0; ci < 8; ++ci) {
      const float* wp = wgb + (size_t)(c0 + ci) * 72;   // wave-uniform
      const float* xrow = &xs[(ci * 9 + 2 * ohl) * 164 + owg * 10];
#pragma unroll
      for (int kh = 0; kh < 3; ++kh) {
        float xv[12];
        const float* xr = xrow + kh * 164;
#pragma unroll
        for (int t2 = 0; t2 < 6; ++t2) {          // 8B-aligned b64 LDS reads
          float2 tt = *(const float2*)(xr + 2 * t2);
          xv[2 * t2] = tt.x; xv[2 * t2 + 1] = tt.y;
        }
#pragma unroll
        for (int kw = 0; kw < 3; ++kw) {
          const float* wk = wp + (kh * 3 + kw) * 8;
#pragma unroll
          for (int j = 0; j < 5; ++j) {
            const float xj = xv[kw + 2 * j];
            acc[0][j] += wk[0] * xj; acc[1][j] += wk[1] * xj;
            acc[2][j] += wk[2] * xj; acc[3][j] += wk[3] * xj;
            acc[4][j] += wk[4] * xj; acc[5][j] += wk[5] * xj;
            acc[6][j] += wk[6] * xj; acc[7][j] += wk[7] * xj;
          }
        }
      }
    }
  }
  // epilogue
  const int oh = oh0 + ohl;
  const int owb = owg * 5;
#pragma unroll
  for (int m = 0; m < 8; ++m) {
    const int co = gg * 8 + m;
    const float bv = b1[co];
    float* op = &feat[(((size_t)n * 512 + co) * 48 + oh) * 80 + owb];
#pragma unroll
    for (int j = 0; j < 5; ++j) op[j] = acc[m][j] + bv;
  }
}

// ---------------- fused heads: blocks [0,120) = conv2 (1x1 bbox), [120,312) = conv3 (3x3 cls)
__global__ __launch_bounds__(256) void heads_k(const float* __restrict__ feat,
                                               const float* __restrict__ wb,
                                               const float* __restrict__ bb,
                                               const float* __restrict__ wcg,
                                               const float* __restrict__ bc,
                                               float* __restrict__ deltas,
                                               float* __restrict__ s) {
  __shared__ float smem[5328];
  const int tid = threadIdx.x;

  if (blockIdx.x < 120) {
    // ---- conv2: 1x1, feat -> deltas[b][pos][36] ----
    float* fs  = smem;          // 16*128
    float* wsb = smem + 2048;   // 16*36
    const int blk = blockIdx.x;
    const int b = blk / 30;
    const int pos0 = (blk % 30) * 128;
    const int pl = tid >> 1, cg = tid & 1;
    const int cbase = cg * 18;
    float acc[18];
#pragma unroll
    for (int j = 0; j < 18; ++j) acc[j] = 0.f;
    const float* fb = feat + (size_t)b * 512 * 3840;

    for (int c0 = 0; c0 < 512; c0 += 16) {
      for (int e = tid; e < 16 * 128; e += 256)
        fs[e] = fb[(size_t)(c0 + (e >> 7)) * 3840 + pos0 + (e & 127)];
      for (int e = tid; e < 16 * 36; e += 256) {
        int ci = e / 36, c = e - ci * 36;
        wsb[e] = wb[(size_t)c * 512 + c0 + ci];
      }
      __syncthreads();
      for (int ci = 0; ci < 16; ++ci) {
        float xv = fs[ci * 128 + pl];
#pragma unroll
        for (int j = 0; j < 18; ++j) acc[j] += xv * wsb[ci * 36 + cbase + j];
      }
      __syncthreads();
    }
    size_t o = ((size_t)b * 3840 + pos0 + pl) * 36 + cbase;
#pragma unroll
    for (int j = 0; j < 18; ++j) deltas[o + j] = acc[j] + bb[cbase + j];
  } else {
    // ---- conv3: 3x3 p1, cls channels 9..17 -> s[b][pos*9+a] ----
    float (*fs)[3][84] = (float(*)[3][84])smem;           // 16*3*84 = 4032
    float (*wc)[9][9]  = (float(*)[9][9])(smem + 4032);   // 16*81 = 1296
    const int bid2 = blockIdx.x - 120;
    const int oh = bid2 % 48;
    const int b = bid2 / 48;
    const int pos = tid % 80;
    const int cg = tid / 80;          // 0..3 (cg==3 idle for compute)
    float acc[3] = {0.f, 0.f, 0.f};
    const float* fb = feat + (size_t)b * 512 * 3840;

    for (int c0 = 0; c0 < 512; c0 += 16) {
      for (int e = tid; e < 16 * 246; e += 256) {
        int ci = e / 246;
        int r = e - ci * 246;
        int ihl = r / 82;
        int iw = r - ihl * 82 - 1;
        int gih = oh - 1 + ihl;
        float v = 0.f;
        if ((unsigned)gih < 48u && (unsigned)iw < 80u)
          v = fb[(size_t)(c0 + ci) * 3840 + gih * 80 + iw];
        fs[ci][ihl][iw + 1] = v;
      }
      for (int e = tid; e < 16 * 81; e += 256) {
        int ci = e / 81;
        int r = e - ci * 81;
        int co = r / 9;
        int k = r - co * 9;
        wc[ci][co][k] = wcg[((size_t)(9 + co) * 512 + c0 + ci) * 9 + k];
      }
      __syncthreads();
      if (cg < 3) {
        const int cb = cg * 3;
        for (int ci = 0; ci < 16; ++ci) {
#pragma unroll
          for (int kh = 0; kh < 3; ++kh) {
#pragma unroll
            for (int kw = 0; kw < 3; ++kw) {
              float xv = fs[ci][kh][pos + kw];
              acc[0] += xv * wc[ci][cb + 0][kh * 3 + kw];
              acc[1] += xv * wc[ci][cb + 1][kh * 3 + kw];
              acc[2] += xv * wc[ci][cb + 2][kh * 3 + kw];
            }
          }
        }
      }
      __syncthreads();
    }
    if (cg < 3) {
      const int cb = cg * 3;
      size_t o = (size_t)b * 34560 + ((size_t)oh * 80 + pos) * 9 + cb;
#pragma unroll
      for (int j = 0; j < 3; ++j) s[o + j] = acc[j] + bc[9 + cb + j];
    }
  }
}

// ---------------- decode: anchors + deltas -> boxes, filtered score keys ----------------
__global__ __launch_bounds__(256) void decode_k(const float* __restrict__ deltas,
                                                const float* __restrict__ s,
                                                float* __restrict__ boxes,
                                                u64* __restrict__ keys) {
  const int g = blockIdx.x * 256 + threadIdx.x;  // < 138240 exactly
  const int b = g / 34560;
  const int i = g - b * 34560;
  const int pos = i / 9;
  const int a = i - pos * 9;
  const int h = pos / 80;
  const int w = pos - h * 80;
  const float gx = (float)(w * 32);
  const float gy = (float)(h * 32);
  const float aw = c_aw[a], ah = c_ah[a];
  const float x1a = 7.5f - 0.5f * (aw - 1.f);   // exact
  const float y1a = 7.5f - 0.5f * (ah - 1.f);   // exact
  const float ws_ = aw, hs_ = ah;               // x2-x1+1 exact
  const float cx = (gx + x1a) + 0.5f * ws_;     // exact
  const float cy = (gy + y1a) + 0.5f * hs_;     // exact

  const float* dp = &deltas[((size_t)b * 3840 + pos) * 36 + a * 4];
  const float d0 = dp[0], d1 = dp[1], d2 = dp[2], d3 = dp[3];
  const float pcx = __fadd_rn(__fmul_rn(d0, ws_), cx);
  const float pcy = __fadd_rn(__fmul_rn(d1, hs_), cy);
  const float pw = __fmul_rn(expf(d2), ws_);
  const float ph = __fmul_rn(expf(d3), hs_);
  float bx1 = __fsub_rn(pcx, __fmul_rn(0.5f, pw));
  float by1 = __fsub_rn(pcy, __fmul_rn(0.5f, ph));
  float bx2 = __fadd_rn(pcx, __fmul_rn(0.5f, pw));
  float by2 = __fadd_rn(pcy, __fmul_rn(0.5f, ph));
  bx1 = fminf(fmaxf(bx1, 0.f), 2559.f);
  by1 = fminf(fmaxf(by1, 0.f), 1535.f);
  bx2 = fminf(fmaxf(bx2, 0.f), 2559.f);
  by2 = fminf(fmaxf(by2, 0.f), 1535.f);
  const float bw = __fadd_rn(__fsub_rn(bx2, bx1), 1.f);
  const float bh = __fadd_rn(__fsub_rn(by2, by1), 1.f);
  float sc = s[g];
  if (!(bw >= 16.f && bh >= 16.f)) sc = -1e30f;

  float4 bo;
  bo.x = bx1; bo.y = by1; bo.z = bx2; bo.w = by2;
  *(float4*)&boxes[(size_t)g * 4] = bo;

  u32 sb = __float_as_uint(sc);
  u32 ou = (sb & 0x80000000u) ? ~sb : (sb | 0x80000000u);
  keys[g] = ((u64)ou << 32) | (u32)(~(u32)i);
}

// ---- select+compact, 2-phase: 14-bit histogram (boundary bin) + exact-rank placement.
__global__ __launch_bounds__(1024) void selcomp_k(const u64* __restrict__ keys,
                                                  u64* __restrict__ sel) {
  __shared__ u32 h[16384];        // 64 KB
  __shared__ u64 cand[6144];      // 48 KB
  __shared__ u32 wsum[16], wsuf[16];
  __shared__ int s_bin, s_above, s_main, s_nc;
  const int b = blockIdx.x;
  const int tid = threadIdx.x;
  const int lane = tid & 63;
  const int wv = tid >> 6;
  const u64* kb = keys + (size_t)b * 34560;

  // phase A: histogram of top-14 bits
#pragma unroll
  for (int q = 0; q < 16; ++q) h[tid + 1024 * q] = 0;
  __syncthreads();
  for (int i = tid; i < 34560; i += 1024)
    atomicAdd(&h[(u32)(kb[i] >> 50)], 1u);
  __syncthreads();

  // hierarchical suffix-sum (3 barriers): thread owns bins [tid*16, tid*16+16)
  const int i0 = tid * 16;
  u32 myb[16];
  u32 tsum = 0;
#pragma unroll
  for (int q = 0; q < 16; ++q) { myb[q] = h[i0 + q]; tsum += myb[q]; }
  u32 sfx = tsum;
#pragma unroll
  for (int off = 1; off < 64; off <<= 1) {
    u32 o = __shfl_down(sfx, off, 64);
    if (lane + off < 64) sfx += o;
  }
  if (lane == 0) wsum[wv] = sfx;   // wave total
  __syncthreads();
  if (tid < 16) {
    u32 v = wsum[tid];
#pragma unroll
    for (int off = 1; off < 16; off <<= 1) {
      u32 o = __shfl_down(v, off, 64);
      if (tid + off < 16) v += o;
    }
    wsuf[tid] = v;                 // sum of wsum[w >= tid]
  }
  __syncthreads();
  const u32 wave_base = (wv < 15) ? wsuf[wv + 1] : 0u;
  u32 accu = wave_base + (sfx - tsum);
#pragma unroll
  for (int q = 15; q >= 0; --q) { accu += myb[q]; h[i0 + q] = accu; }  // suffix incl.
  __syncthreads();

  // boundary bin: h[bin] >= 2000 > h[bin+1]
#pragma unroll
  for (int q = 0; q < 16; ++q) {
    int bn = i0 + q;
    u32 Si = h[bn];
    u32 Sn = (bn < 16383) ? h[bn + 1] : 0u;
    if ((int)Si >= 2000 && (int)Sn < 2000) { s_bin = bn; s_above = (int)Sn; }
  }
  if (tid == 0) { s_main = 0; s_nc = 0; }
  __syncthreads();
  const u32 B = (u32)s_bin;
  const int above = s_above;
  const int need = 2000 - above;

  // phase B: compact mains, gather boundary-bin candidates
  for (int i = tid; i < 34560; i += 1024) {
    u64 k = kb[i];
    u32 t14 = (u32)(k >> 50);
    if (t14 > B) {
      int p = atomicAdd(&s_main, 1);
      sel[(size_t)b * 2048 + p] = k;
    } else if (t14 == B) {
      int p = atomicAdd(&s_nc, 1);
      if (p < 6144) cand[p] = k;
    }
  }
  __syncthreads();
  const int nc = min(s_nc, 6144);
  // exact rank among candidates (unique u64 keys): place top `need`
  for (int c = tid; c < nc; c += 1024) {
    u64 kc = cand[c];
    int rnk = 0;
    for (int j = 0; j < nc; ++j) rnk += (cand[j] > kc) ? 1 : 0;
    if (rnk < need) sel[(size_t)b * 2048 + above + rnk] = kc;
  }
}

// ---------------- sort 2048 keys, emit sorted boxes SoA + validity words ----------------
__global__ __launch_bounds__(1024) void sort_k(const u64* __restrict__ sel,
                                               const float* __restrict__ boxes,
                                               float* __restrict__ sx1, float* __restrict__ sy1,
                                               float* __restrict__ sx2, float* __restrict__ sy2,
                                               float* __restrict__ sar, u32* __restrict__ sval) {
  __shared__ u64 K[2048];
  __shared__ unsigned char val[2048];
  const int b = blockIdx.x;
  const int tid = threadIdx.x;

  for (int i = tid; i < 2048; i += 1024)
    K[i] = (i < 2000) ? sel[(size_t)b * 2048 + i] : 0ull;
  __syncthreads();
  // bitonic sort descending
  for (int k2 = 2; k2 <= 2048; k2 <<= 1) {
    for (int j = k2 >> 1; j > 0; j >>= 1) {
      for (int i = tid; i < 2048; i += 1024) {
        int l = i ^ j;
        if (l > i) {
          u64 a = K[i], c = K[l];
          bool up = ((i & k2) == 0);
          if (up ? (a < c) : (a > c)) { K[i] = c; K[l] = a; }
        }
      }
      __syncthreads();
    }
  }
  // extract boxes/validity in score order -> global SoA
  for (int i = tid; i < 2048; i += 1024) {
    float x1v = 0.f, y1v = 0.f, x2v = 0.f, y2v = 0.f, arv = 1.f;
    unsigned char vb = 0;
    if (i < 2000) {
      u64 key = K[i];
      u32 ou = (u32)(key >> 32);
      int idx = (int)(~(u32)key);
      u32 sb = (ou & 0x80000000u) ? (ou & 0x7FFFFFFFu) : ~ou;
      float sc = __uint_as_float(sb);
      const float4 bo = *(const float4*)&boxes[((size_t)b * 34560 + idx) * 4];
      x1v = bo.x; y1v = bo.y; x2v = bo.z; y2v = bo.w;
      arv = __fmul_rn(__fadd_rn(__fsub_rn(bo.z, bo.x), 1.f),
                      __fadd_rn(__fsub_rn(bo.w, bo.y), 1.f));
      vb = (sc > -5e29f) ? 1 : 0;
    }
    size_t o = (size_t)b * 2048 + i;
    sx1[o] = x1v; sy1[o] = y1v; sx2[o] = x2v; sy2[o] = y2v; sar[o] = arv;
    val[i] = vb;
  }
  __syncthreads();
  if (tid < 64) {
    u32 w = 0;
#pragma unroll
    for (int q = 0; q < 32; ++q)
      w |= (val[tid * 32 + q] ? 1u : 0u) << q;
    sval[b * 64 + tid] = w;
  }
}

// ---------------- IoU suppression bit-matrix: supp[b][i][w] (2048x2048 bits/batch) ----
__global__ __launch_bounds__(256) void iou_k(const float* __restrict__ sx1, const float* __restrict__ sy1,
                                             const float* __restrict__ sx2, const float* __restrict__ sy2,
                                             const float* __restrict__ sar,
                                             u64* __restrict__ supp) {
  __shared__ float lx1[2048], ly1[2048], lx2[2048], ly2[2048], lar[2048];
  const int b = blockIdx.y;
  const int r0 = blockIdx.x * 128;
  const int tid = threadIdx.x;
  const int lane = tid & 63;
  const int wq = tid >> 6;          // wave 0..3
  const size_t base = (size_t)b * 2048;

  for (int i = tid; i < 2048; i += 256) {
    lx1[i] = sx1[base + i]; ly1[i] = sy1[base + i];
    lx2[i] = sx2[base + i]; ly2[i] = sy2[base + i];
    lar[i] = sar[base + i];
  }
  __syncthreads();

  for (int i = r0; i < r0 + 128; ++i) {
    const float px1 = lx1[i], py1 = ly1[i], px2 = lx2[i], py2 = ly2[i], pa = lar[i];
    u64* row = supp + ((size_t)b * 2048 + i) * 32;
#pragma unroll
    for (int s2 = 0; s2 < 8; ++s2) {
      const int j = s2 * 256 + wq * 64 + lane;
      float iw = __fadd_rn(__fsub_rn(fminf(px2, lx2[j]), fmaxf(px1, lx1[j])), 1.f);
      iw = fmaxf(0.f, iw);
      float ih = __fadd_rn(__fsub_rn(fminf(py2, ly2[j]), fmaxf(py1, ly1[j])), 1.f);
      ih = fmaxf(0.f, ih);
      const float inter = __fmul_rn(iw, ih);
      const float denom = __fsub_rn(__fadd_rn(pa, lar[j]), inter);
      const float iou = __fdiv_rn(inter, denom);
      const u64 bits = __ballot(iou > 0.7f);
      if (lane == 0) row[s2 * 4 + wq] = bits;
    }
  }
}

// ---------------- greedy scan: bitset in regs, suppress via precomputed rows ----------
__global__ __launch_bounds__(64) void scan_k(const u32* __restrict__ sval,
                                             const u64* __restrict__ supp,
                                             const float* __restrict__ sx1, const float* __restrict__ sy1,
                                             const float* __restrict__ sx2, const float* __restrict__ sy2,
                                             float* __restrict__ out) {
  const int b = blockIdx.x;
  const int lane = threadIdx.x;
  u32 v = sval[b * 64 + lane];     // lane owns boxes [32*lane, 32*lane+32)
  const size_t base = (size_t)b * 2048;

  int cnt = 0;
  for (int t = 0; t < 300; ++t) {
    u64 m = __ballot(v != 0);
    if (m == 0) break;
    const int f = __ffsll(m) - 1;
    const u32 fw = __shfl(v, f, 64);
    const int p = f * 32 + (__ffs(fw) - 1);    // first valid = pick
    if (lane == 0) {
      float* row = out + ((size_t)b * 300 + t) * 5;
      row[0] = (float)b;
      row[1] = sx1[base + p]; row[2] = sy1[base + p];
      row[3] = sx2[base + p]; row[4] = sy2[base + p];
    }
    cnt = t + 1;
    // v &= ~supp_row[p]; diagonal bit clears the pick itself
    const u64 w8 = supp[(base + p) * 32 + (lane >> 1)];
    const u32 sup = (lane & 1) ? (u32)(w8 >> 32) : (u32)w8;
    v &= ~sup;
  }
  for (int t2 = cnt + lane; t2 < 300; t2 += 64) {
    float* row = out + ((size_t)b * 300 + t2) * 5;
    row[0] = (float)b; row[1] = 0.f; row[2] = 0.f; row[3] = 0.f; row[4] = 0.f;
  }
  if (lane == 0) out[6000 + b] = (float)cnt;
}

// ---------------- launcher ----------------
extern "C" void kernel_launch(void* const* d_in, const int* in_sizes, int n_in,
                              void* d_out, int out_size, void* d_ws, size_t ws_size,
                              hipStream_t stream) {
  const float* x  = (const float*)d_in[0];
  const float* w1 = (const float*)d_in[1];
  const float* b1 = (const float*)d_in[2];
  const float* wb = (const float*)d_in[3];
  const float* bb = (const float*)d_in[4];
  const float* wc = (const float*)d_in[5];
  const float* bc = (const float*)d_in[6];
  float* out = (float*)d_out;
  char* ws = (char*)d_ws;

  float* feat   = (float*)(ws + 0);           // 31,457,280 B
  float* wt2    = (float*)(ws + 31457280);    //  9,437,184 B
  float* deltas = (float*)(ws + 40894464);    //  2,211,840 B
  float* s      = (float*)(ws + 43106304);    //    552,960 B
  float* boxes  = (float*)(ws + 43659264);    //  2,211,840 B
  u64*   keys   = (u64*)  (ws + 45871104);    //  1,105,920 B
  u64*   sel    = (u64*)  (ws + 46977088);    //     65,536 B
  float* sx1    = (float*)(ws + 47042624);    //     32,768 B
  float* sy1    = (float*)(ws + 47075392);    //     32,768 B
  float* sx2    = (float*)(ws + 47108160);    //     32,768 B
  float* sy2    = (float*)(ws + 47140928);    //     32,768 B
  float* sar    = (float*)(ws + 47173696);    //     32,768 B
  u32*   sval   = (u32*)  (ws + 47206464);    //      1,024 B
  u64*   supp   = (u64*)  (ws + 47207488);    //  2,097,152 B  (end 49,304,640)

  hipLaunchKernelGGL(transpose_k, dim3(9216), dim3(256), 0, stream, w1, wt2);
  hipLaunchKernelGGL(conv1_k, dim3(16, 12, 4), dim3(256), 0, stream, x, wt2, b1, feat);
  hipLaunchKernelGGL(heads_k, dim3(312), dim3(256), 0, stream, feat, wb, bb, wc, bc, deltas, s);
  hipLaunchKernelGGL(decode_k, dim3(540), dim3(256), 0, stream, deltas, s, boxes, keys);
  hipLaunchKernelGGL(selcomp_k, dim3(4), dim3(1024), 0, stream, keys, sel);
  hipLaunchKernelGGL(sort_k, dim3(4), dim3(1024), 0, stream, sel, boxes, sx1, sy1, sx2, sy2, sar, sval);
  hipLaunchKernelGGL(iou_k, dim3(16, 4), dim3(256), 0, stream, sx1, sy1, sx2, sy2, sar, supp);
  hipLaunchKernelGGL(scan_k, dim3(4), dim3(64), 0, stream, sval, supp, sx1, sy1, sx2, sy2, out);
}

// Round 13
// 1378.497 us; speedup vs baseline: 2.5382x; 1.1198x over previous
//
#include <hip/hip_runtime.h>
#include <stdint.h>

typedef unsigned long long u64;
typedef unsigned int u32;
typedef float v2f __attribute__((ext_vector_type(2)));

// anchor (w,h) per a = ratio_idx*3 + scale_idx ; ratios (.5,1,2), scales (8,16,32)
__constant__ float c_aw[9] = {184.f,368.f,736.f,128.f,256.f,512.f, 88.f,176.f,352.f};
__constant__ float c_ah[9] = { 96.f,192.f,384.f,128.f,256.f,512.f,176.f,352.f,704.f};

// -------- w1 reorder: w1[co][ci*9+k] -> wt2[g][ci][k][m], co = g*8+m ----------
__global__ __launch_bounds__(256) void transpose_k(const float* __restrict__ w1,
                                                   float* __restrict__ wt2) {
  int e = blockIdx.x * 256 + threadIdx.x;   // < 2359296 exactly
  int m = e & 7;
  int t = e >> 3;
  int k = t % 9;
  int r = t / 9;          // g*512 + ci
  int ci = r & 511;
  int g = r >> 9;
  wt2[e] = w1[(size_t)(g * 8 + m) * 4608 + ci * 9 + k];
}

// ---------------- conv1: x(4,512,96,160) * w s2 p1 -> feat(4,512,48,80)
// r8 structure + co-pair packed FMA (v_pk_fma_f32 probe). Per-chain accumulation
// order (c0 by 8, ci, kh, kw) and FMA semantics bitwise match all passing rounds.
__global__ __launch_bounds__(256, 3) void conv1_k(const float* __restrict__ x,
                                                  const float* __restrict__ wt2,
                                                  const float* __restrict__ b1,
                                                  float* __restrict__ feat) {
  __shared__ float xs[8 * 9 * 164];   // [ci][ih(9)][iw(161) pad 164] = 47232 B
  const int tid = threadIdx.x;
  const int lane = tid & 63;
  const int wv = __builtin_amdgcn_readfirstlane(tid >> 6);   // wave id 0..3
  const int owg = lane & 15;          // 16 groups of 5 ow
  const int ohl = lane >> 4;          // 0..3
  const int n = blockIdx.z;
  const int gg = blockIdx.x * 4 + wv; // global co-group, co = gg*8+m
  const int oh0 = blockIdx.y * 4;
  const int ih_base = 2 * oh0 - 1;

  // ---- c0-invariant staging descriptors (6 strided passes over 1449 elems) ----
  int soff[6], loff[6];
  float okf[6];
  bool act[6];
#pragma unroll
  for (int it = 0; it < 6; ++it) {
    int e2 = tid + 256 * it;
    act[it] = (e2 < 1449);
    int e = act[it] ? e2 : 0;
    int ih = e / 161;
    int c = e - ih * 161;
    int gih = ih_base + ih;
    int giw = c - 1;
    bool ok = act[it] && ((unsigned)gih < 96u) && ((unsigned)giw < 160u);
    soff[it] = min(max(gih, 0), 95) * 160 + min(max(giw, 0), 159);
    loff[it] = ih * 164 + c;
    okf[it] = ok ? 1.f : 0.f;
  }

  v2f acc[4][5];   // co-pairs (2q,2q+1) x 5 ow
#pragma unroll
  for (int q = 0; q < 4; ++q)
#pragma unroll
    for (int j = 0; j < 5; ++j) acc[q][j] = (v2f){0.f, 0.f};

  const float* xb = x + (size_t)n * 512 * 96 * 160;
  const float* wgb = wt2 + (size_t)gg * 512 * 72;   // [ci][k(9)][m(8)]

  // prologue: load chunk c0=0 into regs
  float r[6][8];
#pragma unroll
  for (int it = 0; it < 6; ++it)
#pragma unroll
    for (int ci = 0; ci < 8; ++ci)
      r[it][ci] = xb[(size_t)ci * 15360 + soff[it]];

  for (int c0 = 0; c0 < 512; c0 += 8) {
    __syncthreads();   // previous compute finished; xs free for overwrite
#pragma unroll
    for (int it = 0; it < 6; ++it) {
      if (act[it]) {
        const float m_ = okf[it];
#pragma unroll
        for (int ci = 0; ci < 8; ++ci)
          xs[loff[it] + ci * 1476] = m_ * r[it][ci];   // 1476 = 9*164
      }
    }
    __syncthreads();
    // issue prefetch for c0+8 (fly during compute below)
    if (c0 + 8 < 512) {
      const float* xn = xb + (size_t)(c0 + 8) * 15360;
#pragma unroll
      for (int it = 0; it < 6; ++it)
#pragma unroll
        for (int ci = 0; ci < 8; ++ci)
          r[it][ci] = xn[(size_t)ci * 15360 + soff[it]];
    }

    for (int ci = 0; ci < 8; ++ci) {
      const float* wp = wgb + (size_t)(c0 + ci) * 72;   // wave-uniform
      const float* xrow = &xs[(ci * 9 + 2 * ohl) * 164 + owg * 10];
#pragma unroll
      for (int kh = 0; kh < 3; ++kh) {
        float xv[12];
        const float* xr = xrow + kh * 164;
#pragma unroll
        for (int t2 = 0; t2 < 6; ++t2) {          // 8B-aligned b64 LDS reads
          float2 tt = *(const float2*)(xr + 2 * t2);
          xv[2 * t2] = tt.x; xv[2 * t2 + 1] = tt.y;
        }
#pragma unroll
        for (int kw = 0; kw < 3; ++kw) {
          const v2f* wk2 = (const v2f*)(wp + (kh * 3 + kw) * 8);
          const v2f w0 = wk2[0], w1 = wk2[1], w2 = wk2[2], w3 = wk2[3];
#pragma unroll
          for (int j = 0; j < 5; ++j) {
            const float xj = xv[kw + 2 * j];
            const v2f xx = {xj, xj};
            acc[0][j] = __builtin_elementwise_fma(w0, xx, acc[0][j]);
            acc[1][j] = __builtin_elementwise_fma(w1, xx, acc[1][j]);
            acc[2][j] = __builtin_elementwise_fma(w2, xx, acc[2][j]);
            acc[3][j] = __builtin_elementwise_fma(w3, xx, acc[3][j]);
          }
        }
      }
    }
  }
  // epilogue
  const int oh = oh0 + ohl;
  const int owb = owg * 5;
#pragma unroll
  for (int q = 0; q < 4; ++q) {
    const int co = gg * 8 + 2 * q;
    const float bx = b1[co], by = b1[co + 1];
    float* opx = &feat[(((size_t)n * 512 + co) * 48 + oh) * 80 + owb];
    float* opy = opx + 3840;   // next co plane (48*80)
#pragma unroll
    for (int j = 0; j < 5; ++j) {
      opx[j] = acc[q][j].x + bx;
      opy[j] = acc[q][j].y + by;
    }
  }
}

// ---------------- fused heads (register-prefetch pipelined):
// blocks [0,120) = conv2 (1x1 bbox), [120,312) = conv3 (3x3 cls)
__global__ __launch_bounds__(256) void heads_k(const float* __restrict__ feat,
                                               const float* __restrict__ wb,
                                               const float* __restrict__ bb,
                                               const float* __restrict__ wcg,
                                               const float* __restrict__ bc,
                                               float* __restrict__ deltas,
                                               float* __restrict__ s) {
  __shared__ float smem[5328];
  const int tid = threadIdx.x;

  if (blockIdx.x < 120) {
    // ---- conv2: 1x1, feat -> deltas[b][pos][36] ----
    float* fs  = smem;          // 16*128
    float* wsb = smem + 2048;   // 16*36
    const int blk = blockIdx.x;
    const int b = blk / 30;
    const int pos0 = (blk % 30) * 128;
    const int pl = tid >> 1, cg = tid & 1;
    const int cbase = cg * 18;
    const float* fb = feat + (size_t)b * 512 * 3840;

    int fso[8];
#pragma unroll
    for (int p = 0; p < 8; ++p) {
      int e = tid + 256 * p;
      fso[p] = (e >> 7) * 3840 + pos0 + (e & 127);
    }
    int wso[3]; bool wact[3];
#pragma unroll
    for (int p = 0; p < 3; ++p) {
      int e = tid + 256 * p;
      wact[p] = (e < 576);
      int ee = wact[p] ? e : 0;
      wso[p] = (ee % 36) * 512 + (ee / 36);
    }
    float acc[18];
#pragma unroll
    for (int j = 0; j < 18; ++j) acc[j] = 0.f;

    float rf[8], rw[3];
#pragma unroll
    for (int p = 0; p < 8; ++p) rf[p] = fb[fso[p]];
#pragma unroll
    for (int p = 0; p < 3; ++p) rw[p] = wb[wso[p]];

    for (int t = 0; t < 32; ++t) {
      __syncthreads();
#pragma unroll
      for (int p = 0; p < 8; ++p) fs[tid + 256 * p] = rf[p];
#pragma unroll
      for (int p = 0; p < 3; ++p)
        if (wact[p]) wsb[tid + 256 * p] = rw[p];
      __syncthreads();
      if (t < 31) {
        const float* fn = fb + (size_t)(t + 1) * 16 * 3840;
        const float* wn = wb + (t + 1) * 16;
#pragma unroll
        for (int p = 0; p < 8; ++p) rf[p] = fn[fso[p]];
#pragma unroll
        for (int p = 0; p < 3; ++p) rw[p] = wn[wso[p]];
      }
      for (int ci = 0; ci < 16; ++ci) {
        float xv = fs[ci * 128 + pl];
#pragma unroll
        for (int j = 0; j < 18; ++j) acc[j] += xv * wsb[ci * 36 + cbase + j];
      }
    }
    size_t o = ((size_t)b * 3840 + pos0 + pl) * 36 + cbase;
#pragma unroll
    for (int j = 0; j < 18; ++j) deltas[o + j] = acc[j] + bb[cbase + j];
  } else {
    // ---- conv3: 3x3 p1, cls channels 9..17 -> s[b][pos*9+a] ----
    float* fsf = smem;                 // [ci][ihl][84] flat, 4032
    float* wcf = smem + 4032;          // [ci*81 + co*9 + k], 1296
    const int bid2 = blockIdx.x - 120;
    const int oh = bid2 % 48;
    const int b = bid2 / 48;
    const int pos = tid % 80;
    const int cg = tid / 80;          // 0..3 (cg==3 idle for compute)
    const float* fb = feat + (size_t)b * 512 * 3840;

    int fso3[16], lof3[16];
    float fok3[16];
    bool fact3[16];
#pragma unroll
    for (int p = 0; p < 16; ++p) {
      int e = tid + 256 * p;
      fact3[p] = (e < 3936);
      int ee = fact3[p] ? e : 0;
      int ci = ee / 246;
      int r = ee - ci * 246;
      int ihl = r / 82;
      int iw = r - ihl * 82 - 1;
      int gih = oh - 1 + ihl;
      bool ok = fact3[p] && ((unsigned)gih < 48u) && ((unsigned)iw < 80u);
      fso3[p] = ci * 3840 + min(max(gih, 0), 47) * 80 + min(max(iw, 0), 79);
      lof3[p] = ci * 252 + ihl * 84 + iw + 1;
      fok3[p] = ok ? 1.f : 0.f;
    }
    int wso3[6]; bool wact3[6];
#pragma unroll
    for (int p = 0; p < 6; ++p) {
      int e = tid + 256 * p;
      wact3[p] = (e < 1296);
      int ee = wact3[p] ? e : 0;
      int ci = ee / 81;
      int r = ee - ci * 81;
      int co = r / 9;
      int k = r - co * 9;
      wso3[p] = ((size_t)(9 + co) * 512 + ci) * 9 + k;
    }
    float acc[3] = {0.f, 0.f, 0.f};

    float rf3[16], rw3[6];
#pragma unroll
    for (int p = 0; p < 16; ++p) rf3[p] = fb[fso3[p]];
#pragma unroll
    for (int p = 0; p < 6; ++p) rw3[p] = wcg[wso3[p]];

    for (int t = 0; t < 32; ++t) {
      __syncthreads();
#pragma unroll
      for (int p = 0; p < 16; ++p)
        if (fact3[p]) fsf[lof3[p]] = fok3[p] * rf3[p];
#pragma unroll
      for (int p = 0; p < 6; ++p)
        if (wact3[p]) wcf[tid + 256 * p] = rw3[p];
      __syncthreads();
      if (t < 31) {
        const float* fn = fb + (size_t)(t + 1) * 16 * 3840;
        const float* wn = wcg + (t + 1) * 144;
#pragma unroll
        for (int p = 0; p < 16; ++p) rf3[p] = fn[fso3[p]];
#pragma unroll
        for (int p = 0; p < 6; ++p) rw3[p] = wn[wso3[p]];
      }
      if (cg < 3) {
        const int cb = cg * 3;
        for (int ci = 0; ci < 16; ++ci) {
#pragma unroll
          for (int kh = 0; kh < 3; ++kh) {
#pragma unroll
            for (int kw = 0; kw < 3; ++kw) {
              float xv = fsf[ci * 252 + kh * 84 + pos + kw];
              acc[0] += xv * wcf[ci * 81 + (cb + 0) * 9 + kh * 3 + kw];
              acc[1] += xv * wcf[ci * 81 + (cb + 1) * 9 + kh * 3 + kw];
              acc[2] += xv * wcf[ci * 81 + (cb + 2) * 9 + kh * 3 + kw];
            }
          }
        }
      }
    }
    if (cg < 3) {
      const int cb = cg * 3;
      size_t o = (size_t)b * 34560 + ((size_t)oh * 80 + pos) * 9 + cb;
#pragma unroll
      for (int j = 0; j < 3; ++j) s[o + j] = acc[j] + bc[9 + cb + j];
    }
  }
}

// ---------------- decode: anchors + deltas -> boxes, filtered score keys ----------------
__global__ __launch_bounds__(256) void decode_k(const float* __restrict__ deltas,
                                                const float* __restrict__ s,
                                                float* __restrict__ boxes,
                                                u64* __restrict__ keys) {
  const int g = blockIdx.x * 256 + threadIdx.x;  // < 138240 exactly
  const int b = g / 34560;
  const int i = g - b * 34560;
  const int pos = i / 9;
  const int a = i - pos * 9;
  const int h = pos / 80;
  const int w = pos - h * 80;
  const float gx = (float)(w * 32);
  const float gy = (float)(h * 32);
  const float aw = c_aw[a], ah = c_ah[a];
  const float x1a = 7.5f - 0.5f * (aw - 1.f);   // exact
  const float y1a = 7.5f - 0.5f * (ah - 1.f);   // exact
  const float ws_ = aw, hs_ = ah;               // x2-x1+1 exact
  const float cx = (gx + x1a) + 0.5f * ws_;     // exact
  const float cy = (gy + y1a) + 0.5f * hs_;     // exact

  const float* dp = &deltas[((size_t)b * 3840 + pos) * 36 + a * 4];
  const float d0 = dp[0], d1 = dp[1], d2 = dp[2], d3 = dp[3];
  const float pcx = __fadd_rn(__fmul_rn(d0, ws_), cx);
  const float pcy = __fadd_rn(__fmul_rn(d1, hs_), cy);
  const float pw = __fmul_rn(expf(d2), ws_);
  const float ph = __fmul_rn(expf(d3), hs_);
  float bx1 = __fsub_rn(pcx, __fmul_rn(0.5f, pw));
  float by1 = __fsub_rn(pcy, __fmul_rn(0.5f, ph));
  float bx2 = __fadd_rn(pcx, __fmul_rn(0.5f, pw));
  float by2 = __fadd_rn(pcy, __fmul_rn(0.5f, ph));
  bx1 = fminf(fmaxf(bx1, 0.f), 2559.f);
  by1 = fminf(fmaxf(by1, 0.f), 1535.f);
  bx2 = fminf(fmaxf(bx2, 0.f), 2559.f);
  by2 = fminf(fmaxf(by2, 0.f), 1535.f);
  const float bw = __fadd_rn(__fsub_rn(bx2, bx1), 1.f);
  const float bh = __fadd_rn(__fsub_rn(by2, by1), 1.f);
  float sc = s[g];
  if (!(bw >= 16.f && bh >= 16.f)) sc = -1e30f;

  float4 bo;
  bo.x = bx1; bo.y = by1; bo.z = bx2; bo.w = by2;
  *(float4*)&boxes[(size_t)g * 4] = bo;

  u32 sb = __float_as_uint(sc);
  u32 ou = (sb & 0x80000000u) ? ~sb : (sb | 0x80000000u);
  keys[g] = ((u64)ou << 32) | (u32)(~(u32)i);
}

// ---- select+compact, 2-phase: 14-bit histogram (boundary bin) + exact-rank placement.
__global__ __launch_bounds__(1024) void selcomp_k(const u64* __restrict__ keys,
                                                  u64* __restrict__ sel) {
  __shared__ u32 h[16384];        // 64 KB
  __shared__ u64 cand[6144];      // 48 KB
  __shared__ u32 wsum[16], wsuf[16];
  __shared__ int s_bin, s_above, s_main, s_nc;
  const int b = blockIdx.x;
  const int tid = threadIdx.x;
  const int lane = tid & 63;
  const int wv = tid >> 6;
  const u64* kb = keys + (size_t)b * 34560;

  // phase A: histogram of top-14 bits
#pragma unroll
  for (int q = 0; q < 16; ++q) h[tid + 1024 * q] = 0;
  __syncthreads();
  for (int i = tid; i < 34560; i += 1024)
    atomicAdd(&h[(u32)(kb[i] >> 50)], 1u);
  __syncthreads();

  // hierarchical suffix-sum (3 barriers): thread owns bins [tid*16, tid*16+16)
  const int i0 = tid * 16;
  u32 myb[16];
  u32 tsum = 0;
#pragma unroll
  for (int q = 0; q < 16; ++q) { myb[q] = h[i0 + q]; tsum += myb[q]; }
  u32 sfx = tsum;
#pragma unroll
  for (int off = 1; off < 64; off <<= 1) {
    u32 o = __shfl_down(sfx, off, 64);
    if (lane + off < 64) sfx += o;
  }
  if (lane == 0) wsum[wv] = sfx;   // wave total
  __syncthreads();
  if (tid < 16) {
    u32 v = wsum[tid];
#pragma unroll
    for (int off = 1; off < 16; off <<= 1) {
      u32 o = __shfl_down(v, off, 64);
      if (tid + off < 16) v += o;
    }
    wsuf[tid] = v;                 // sum of wsum[w >= tid]
  }
  __syncthreads();
  const u32 wave_base = (wv < 15) ? wsuf[wv + 1] : 0u;
  u32 accu = wave_base + (sfx - tsum);
#pragma unroll
  for (int q = 15; q >= 0; --q) { accu += myb[q]; h[i0 + q] = accu; }  // suffix incl.
  __syncthreads();

  // boundary bin: h[bin] >= 2000 > h[bin+1]
#pragma unroll
  for (int q = 0; q < 16; ++q) {
    int bn = i0 + q;
    u32 Si = h[bn];
    u32 Sn = (bn < 16383) ? h[bn + 1] : 0u;
    if ((int)Si >= 2000 && (int)Sn < 2000) { s_bin = bn; s_above = (int)Sn; }
  }
  if (tid == 0) { s_main = 0; s_nc = 0; }
  __syncthreads();
  const u32 B = (u32)s_bin;
  const int above = s_above;
  const int need = 2000 - above;

  // phase B: compact mains, gather boundary-bin candidates
  for (int i = tid; i < 34560; i += 1024) {
    u64 k = kb[i];
    u32 t14 = (u32)(k >> 50);
    if (t14 > B) {
      int p = atomicAdd(&s_main, 1);
      sel[(size_t)b * 2048 + p] = k;
    } else if (t14 == B) {
      int p = atomicAdd(&s_nc, 1);
      if (p < 6144) cand[p] = k;
    }
  }
  __syncthreads();
  const int nc = min(s_nc, 6144);
  // exact rank among candidates (unique u64 keys): place top `need`
  for (int c = tid; c < nc; c += 1024) {
    u64 kc = cand[c];
    int rnk = 0;
    for (int j = 0; j < nc; ++j) rnk += (cand[j] > kc) ? 1 : 0;
    if (rnk < need) sel[(size_t)b * 2048 + above + rnk] = kc;
  }
}

// ---------------- sort 2048 keys, emit sorted boxes SoA + validity words ----------------
__global__ __launch_bounds__(1024) void sort_k(const u64* __restrict__ sel,
                                               const float* __restrict__ boxes,
                                               float* __restrict__ sx1, float* __restrict__ sy1,
                                               float* __restrict__ sx2, float* __restrict__ sy2,
                                               float* __restrict__ sar, u32* __restrict__ sval) {
  __shared__ u64 K[2048];
  __shared__ unsigned char val[2048];
  const int b = blockIdx.x;
  const int tid = threadIdx.x;

  for (int i = tid; i < 2048; i += 1024)
    K[i] = (i < 2000) ? sel[(size_t)b * 2048 + i] : 0ull;
  __syncthreads();
  // bitonic sort descending
  for (int k2 = 2; k2 <= 2048; k2 <<= 1) {
    for (int j = k2 >> 1; j > 0; j >>= 1) {
      for (int i = tid; i < 2048; i += 1024) {
        int l = i ^ j;
        if (l > i) {
          u64 a = K[i], c = K[l];
          bool up = ((i & k2) == 0);
          if (up ? (a < c) : (a > c)) { K[i] = c; K[l] = a; }
        }
      }
      __syncthreads();
    }
  }
  // extract boxes/validity in score order -> global SoA
  for (int i = tid; i < 2048; i += 1024) {
    float x1v = 0.f, y1v = 0.f, x2v = 0.f, y2v = 0.f, arv = 1.f;
    unsigned char vb = 0;
    if (i < 2000) {
      u64 key = K[i];
      u32 ou = (u32)(key >> 32);
      int idx = (int)(~(u32)key);
      u32 sb = (ou & 0x80000000u) ? (ou & 0x7FFFFFFFu) : ~ou;
      float sc = __uint_as_float(sb);
      const float4 bo = *(const float4*)&boxes[((size_t)b * 34560 + idx) * 4];
      x1v = bo.x; y1v = bo.y; x2v = bo.z; y2v = bo.w;
      arv = __fmul_rn(__fadd_rn(__fsub_rn(bo.z, bo.x), 1.f),
                      __fadd_rn(__fsub_rn(bo.w, bo.y), 1.f));
      vb = (sc > -5e29f) ? 1 : 0;
    }
    size_t o = (size_t)b * 2048 + i;
    sx1[o] = x1v; sy1[o] = y1v; sx2[o] = x2v; sy2[o] = y2v; sar[o] = arv;
    val[i] = vb;
  }
  __syncthreads();
  if (tid < 64) {
    u32 w = 0;
#pragma unroll
    for (int q = 0; q < 32; ++q)
      w |= (val[tid * 32 + q] ? 1u : 0u) << q;
    sval[b * 64 + tid] = w;
  }
}

// ---------------- IoU suppression bit-matrix: supp[b][i][w] (2048x2048 bits/batch) ----
__global__ __launch_bounds__(256) void iou_k(const float* __restrict__ sx1, const float* __restrict__ sy1,
                                             const float* __restrict__ sx2, const float* __restrict__ sy2,
                                             const float* __restrict__ sar,
                                             u64* __restrict__ supp) {
  __shared__ float lx1[2048], ly1[2048], lx2[2048], ly2[2048], lar[2048];
  const int b = blockIdx.y;
  const int r0 = blockIdx.x * 128;
  const int tid = threadIdx.x;
  const int lane = tid & 63;
  const int wq = tid >> 6;          // wave 0..3
  const size_t base = (size_t)b * 2048;

  for (int i = tid; i < 2048; i += 256) {
    lx1[i] = sx1[base + i]; ly1[i] = sy1[base + i];
    lx2[i] = sx2[base + i]; ly2[i] = sy2[base + i];
    lar[i] = sar[base + i];
  }
  __syncthreads();

  for (int i = r0; i < r0 + 128; ++i) {
    const float px1 = lx1[i], py1 = ly1[i], px2 = lx2[i], py2 = ly2[i], pa = lar[i];
    u64* row = supp + ((size_t)b * 2048 + i) * 32;
#pragma unroll
    for (int s2 = 0; s2 < 8; ++s2) {
      const int j = s2 * 256 + wq * 64 + lane;
      float iw = __fadd_rn(__fsub_rn(fminf(px2, lx2[j]), fmaxf(px1, lx1[j])), 1.f);
      iw = fmaxf(0.f, iw);
      float ih = __fadd_rn(__fsub_rn(fminf(py2, ly2[j]), fmaxf(py1, ly1[j])), 1.f);
      ih = fmaxf(0.f, ih);
      const float inter = __fmul_rn(iw, ih);
      const float denom = __fsub_rn(__fadd_rn(pa, lar[j]), inter);
      const float iou = __fdiv_rn(inter, denom);
      const u64 bits = __ballot(iou > 0.7f);
      if (lane == 0) row[s2 * 4 + wq] = bits;
    }
  }
}

// ---------------- greedy scan: bitset in regs, suppress via precomputed rows ----------
__global__ __launch_bounds__(64) void scan_k(const u32* __restrict__ sval,
                                             const u64* __restrict__ supp,
                                             const float* __restrict__ sx1, const float* __restrict__ sy1,
                                             const float* __restrict__ sx2, const float* __restrict__ sy2,
                                             float* __restrict__ out) {
  const int b = blockIdx.x;
  const int lane = threadIdx.x;
  u32 v = sval[b * 64 + lane];     // lane owns boxes [32*lane, 32*lane+32)
  const size_t base = (size_t)b * 2048;

  int cnt = 0;
  for (int t = 0; t < 300; ++t) {
    u64 m = __ballot(v != 0);
    if (m == 0) break;
    const int f = __ffsll(m) - 1;
    const u32 fw = __shfl(v, f, 64);
    const int p = f * 32 + (__ffs(fw) - 1);    // first valid = pick
    if (lane == 0) {
      float* row = out + ((size_t)b * 300 + t) * 5;
      row[0] = (float)b;
      row[1] = sx1[base + p]; row[2] = sy1[base + p];
      row[3] = sx2[base + p]; row[4] = sy2[base + p];
    }
    cnt = t + 1;
    // v &= ~supp_row[p]; diagonal bit clears the pick itself
    const u64 w8 = supp[(base + p) * 32 + (lane >> 1)];
    const u32 sup = (lane & 1) ? (u32)(w8 >> 32) : (u32)w8;
    v &= ~sup;
  }
  for (int t2 = cnt + lane; t2 < 300; t2 += 64) {
    float* row = out + ((size_t)b * 300 + t2) * 5;
    row[0] = (float)b; row[1] = 0.f; row[2] = 0.f; row[3] = 0.f; row[4] = 0.f;
  }
  if (lane == 0) out[6000 + b] = (float)cnt;
}

// ---------------- launcher ----------------
extern "C" void kernel_launch(void* const* d_in, const int* in_sizes, int n_in,
                              void* d_out, int out_size, void* d_ws, size_t ws_size,
                              hipStream_t stream) {
  const float* x  = (const float*)d_in[0];
  const float* w1 = (const float*)d_in[1];
  const float* b1 = (const float*)d_in[2];
  const float* wb = (const float*)d_in[3];
  const float* bb = (const float*)d_in[4];
  const float* wc = (const float*)d_in[5];
  const float* bc = (const float*)d_in[6];
  float* out = (float*)d_out;
  char* ws = (char*)d_ws;

  float* feat   = (float*)(ws + 0);           // 31,457,280 B
  float* wt2    = (float*)(ws + 31457280);    //  9,437,184 B
  float* deltas = (float*)(ws + 40894464);    //  2,211,840 B
  float* s      = (float*)(ws + 43106304);    //    552,960 B
  float* boxes  = (float*)(ws + 43659264);    //  2,211,840 B
  u64*   keys   = (u64*)  (ws + 45871104);    //  1,105,920 B
  u64*   sel    = (u64*)  (ws + 46977088);    //     65,536 B
  float* sx1    = (float*)(ws + 47042624);    //     32,768 B
  float* sy1    = (float*)(ws + 47075392);    //     32,768 B
  float* sx2    = (float*)(ws + 47108160);    //     32,768 B
  float* sy2    = (float*)(ws + 47140928);    //     32,768 B
  float* sar    = (float*)(ws + 47173696);    //     32,768 B
  u32*   sval   = (u32*)  (ws + 47206464);    //      1,024 B
  u64*   supp   = (u64*)  (ws + 47207488);    //  2,097,152 B  (end 49,304,640)

  hipLaunchKernelGGL(transpose_k, dim3(9216), dim3(256), 0, stream, w1, wt2);
  hipLaunchKernelGGL(conv1_k, dim3(16, 12, 4), dim3(256), 0, stream, x, wt2, b1, feat);
  hipLaunchKernelGGL(heads_k, dim3(312), dim3(256), 0, stream, feat, wb, bb, wc, bc, deltas, s);
  hipLaunchKernelGGL(decode_k, dim3(540), dim3(256), 0, stream, deltas, s, boxes, keys);
  hipLaunchKernelGGL(selcomp_k, dim3(4), dim3(1024), 0, stream, keys, sel);
  hipLaunchKernelGGL(sort_k, dim3(4), dim3(1024), 0, stream, sel, boxes, sx1, sy1, sx2, sy2, sar, sval);
  hipLaunchKernelGGL(iou_k, dim3(16, 4), dim3(256), 0, stream, sx1, sy1, sx2, sy2, sar, supp);
  hipLaunchKernelGGL(scan_k, dim3(4), dim3(64), 0, stream, sval, supp, sx1, sy1, sx2, sy2, out);
}